// Round 6
// baseline (554.281 us; speedup 1.0000x reference)
//
#include <hip/hip_runtime.h>

// C51 distributional Q target: operand-swapped MFMA (D = W * X^T), each lane
// owns 4 consecutive FEATURES of one batch ROW; LN/SiLU/softmax in registers.
// R6: 16 rows/block (rt dim removed), single 16KB time-multiplexed LDS region
// (X->H1->H2->H3->proj), ~19KB total -> 8 blocks/CU by LDS; launch_bounds
// (256,6) => 6 blocks/CU by VGPR (cap 85) = 24 waves/CU. v_cvt_pk_bf16_f32
// for packing (1 inst / 2 values).

#define THREADS 256
#define PREP_THREADS 256

typedef __attribute__((ext_vector_type(8))) short short8v;
typedef __attribute__((ext_vector_type(4))) float f32x4;

__device__ __forceinline__ unsigned short f2bf(float f) {
  union { float f; unsigned u; } v; v.f = f;
  unsigned u = v.u;
  u += 0x7fffu + ((u >> 16) & 1u);   // RNE
  return (unsigned short)(u >> 16);
}
// HW packed fp32->bf16 (RNE), 1 VALU inst for 2 values
__device__ __forceinline__ unsigned pack2bf(float a, float b) {
  unsigned r;
  asm("v_cvt_pk_bf16_f32 %0, %1, %2" : "=v"(r) : "v"(a), "v"(b));
  return r;
}

// ---------------- prep: weights fp32 [K][N] -> bf16 [N][K] in ws -------------
// W1T @0 (512x160), W2T @81920 (256x512), W3T @212992 (128x256),
// W4T @245760 (256x128, rows n>=251 zero-padded)
__global__ void prep_kernel(const float* __restrict__ W1, const float* __restrict__ W2,
                            const float* __restrict__ W3, const float* __restrict__ W4,
                            unsigned short* __restrict__ ws) {
  int i = blockIdx.x * PREP_THREADS + threadIdx.x;
  if (i < 81920) {
    int n = i / 160, k = i - n * 160;
    ws[i] = f2bf(W1[k * 512 + n]);
  } else if (i < 212992) {
    int j = i - 81920; int n = j >> 9, k = j & 511;
    ws[i] = f2bf(W2[k * 256 + n]);
  } else if (i < 245760) {
    int j = i - 212992; int n = j >> 8, k = j & 255;
    ws[i] = f2bf(W3[k * 128 + n]);
  } else if (i < 278528) {
    int j = i - 245760; int n = j >> 7, k = j & 127;
    ws[i] = (n < 251) ? f2bf(W4[k * 251 + n]) : (unsigned short)0;
  }
}

// LDS layout (bytes). ONE time-multiplexed 16KB region R @0:
//   X bf16 [16][160] swz -> H1 bf16 [16][512] swz -> H2 [16][256] ->
//   H3 [16][128] -> proj f32 [16][251] (16064B)
// Every overwrite is fenced by the LN reduction's internal __syncthreads
// (all waves have finished reading the previous tenant before any store).
#define OFF_R   0
#define OFF_ZS  16384
#define OFF_B4  17408
#define OFF_RED 18432
#define LDS_TOTAL 19008

// GEMM: acc[ft] += WT[fbase+ft*16+..][k] * H[lm][k]
// MFMA 16x16x32 bf16, A = weight rows (m=feature), B = act rows (n=batch row).
// D: lane&15 = batch row, (lane>>4)*4+reg = feature-in-tile.
// Depth-1 double-buffer, compile-time ring indices; single woff VGPR
// (ft/ks offsets are compile-time constants).
template<int KD, int NFT>
__device__ __forceinline__ void gemm_w(const unsigned short* __restrict__ WT,
                                       const unsigned char* __restrict__ Hb,
                                       int fbase, f32x4 (&acc)[NFT]) {
  const int lane = threadIdx.x & 63;
  const int lm = lane & 15, kg = lane >> 4;
  constexpr int KS  = KD / 32;
  constexpr int G   = (NFT > 4) ? 2 : 1;   // ft groups (cap live a-frags at 4)
  constexpr int FPG = NFT / G;
  constexpr int NIT = KS * G;

  const int woff0 = (fbase + lm) * KD + kg * 8;
  // b-frag LDS byte offsets: per-ks-parity (swizzle XOR covers bits 4..6;
  // bit6 of ks*64 folds into parity, higher bits advance linearly by 128B).
  const int r = lm;
  const int swz = (r & 7) << 4;
  const int bbase = r * (KD * 2) + kg * 16;
  const int boff0 = bbase ^ swz;
  const int boff1 = (bbase + 64) ^ swz;

  short8v abuf[2][FPG];
  short8v bbuf[2];
  bbuf[0] = *(const short8v*)(Hb + boff0);
#pragma unroll
  for (int f = 0; f < FPG; ++f)
    abuf[0][f] = *(const short8v*)(WT + woff0 + f * (16 * KD));

#pragma unroll
  for (int it = 0; it < NIT; ++it) {
    const int ks = it / G, g = it % G;
    const int cur = it & 1, nxt = cur ^ 1;
    if (it + 1 < NIT) {
      const int nit = it + 1;
      const int nks = nit / G, ng = nit % G;
      if (ng == 0) {
        const int koff = (nks >> 1) * 128;
        bbuf[nks & 1] = *(const short8v*)(Hb + ((nks & 1) ? boff1 : boff0) + koff);
      }
#pragma unroll
      for (int f = 0; f < FPG; ++f)
        abuf[nxt][f] = *(const short8v*)(WT + woff0 + (ng * FPG + f) * (16 * KD) + nks * 32);
    }
#pragma unroll
    for (int f = 0; f < FPG; ++f) {
      const int ft = g * FPG + f;
      acc[ft] = __builtin_amdgcn_mfma_f32_16x16x32_bf16(abuf[cur][f], bbuf[ks & 1], acc[ft], 0, 0, 0);
    }
  }
}

// bias + LayerNorm + SiLU entirely in registers, then one packed b64 store
// per ft into swizzled LDS [16][ND] bf16. 4 waves reduce via redL (stride 9).
// Internal barrier doubles as the region-reuse fence.
template<int ND, int NFT>
__device__ __forceinline__ void ln_silu_store(
    f32x4 (&acc)[NFT],
    const float* __restrict__ bias, const float* __restrict__ g,
    const float* __restrict__ be, unsigned char* __restrict__ Hb,
    float* __restrict__ redL, int fbase, int fq)
{
  const int lane = threadIdx.x & 63;
  const int lm = lane & 15, kg = lane >> 4;
  float s = 0.f, q = 0.f;
#pragma unroll
  for (int ft = 0; ft < NFT; ++ft) {
    const int f0 = fbase + ft * 16 + kg * 4;
    const f32x4 bb = *(const f32x4*)(bias + f0);
#pragma unroll
    for (int rg = 0; rg < 4; ++rg) {
      float x = acc[ft][rg] + bb[rg];
      acc[ft][rg] = x;
      s += x; q += x * x;
    }
  }
  s += __shfl_xor(s, 16); s += __shfl_xor(s, 32);
  q += __shfl_xor(q, 16); q += __shfl_xor(q, 32);
  if (lane < 16) {
    redL[lm * 9 + fq * 2    ] = s;
    redL[lm * 9 + fq * 2 + 1] = q;
  }
  __syncthreads();
  float S = 0.f, Q = 0.f;
#pragma unroll
  for (int w = 0; w < 4; ++w) {
    S += redL[lm * 9 + w * 2];
    Q += redL[lm * 9 + w * 2 + 1];
  }
  const float mean = S * (1.0f / ND);
  const float var  = Q * (1.0f / ND) - mean * mean;
  const float rstd = rsqrtf(var + 1e-5f);
#pragma unroll
  for (int ft = 0; ft < NFT; ++ft) {
    const int f0 = fbase + ft * 16 + kg * 4;
    const f32x4 g4 = *(const f32x4*)(g + f0);
    const f32x4 e4 = *(const f32x4*)(be + f0);
    float h[4];
#pragma unroll
    for (int rg = 0; rg < 4; ++rg) {
      float y = (acc[ft][rg] - mean) * rstd * g4[rg] + e4[rg];
      h[rg] = y * (1.0f / (1.0f + __expf(-y)));
    }
    uint2 w; w.x = pack2bf(h[0], h[1]); w.y = pack2bf(h[2], h[3]);
    int byte = lm * (ND * 2) + f0 * 2;
    byte ^= ((lm & 7) << 4);
    *(uint2*)(Hb + byte) = w;
  }
}

__global__ __launch_bounds__(THREADS, 6) void fused_kernel(
    const float* __restrict__ obs, const float* __restrict__ actions,
    const float* __restrict__ rewards, const float* __restrict__ bootstrap,
    const float* __restrict__ discount, const float* __restrict__ q_support,
    const float* __restrict__ b1, const float* __restrict__ g1, const float* __restrict__ be1,
    const float* __restrict__ b2, const float* __restrict__ g2, const float* __restrict__ be2,
    const float* __restrict__ b3, const float* __restrict__ g3, const float* __restrict__ be3,
    const float* __restrict__ b4,
    const unsigned short* __restrict__ ws,
    float* __restrict__ out)
{
  __shared__ __align__(16) unsigned char smem[LDS_TOTAL];
  const int tid  = threadIdx.x;
  const int fq   = tid >> 6;          // wave = feature-quarter, 0..3
  const int lane = tid & 63;
  const int lm   = lane & 15;
  const int kg   = lane >> 4;
  const int row0 = blockIdx.x * 16;

  const unsigned short* W1T = ws;
  const unsigned short* W2T = ws + 81920;
  const unsigned short* W3T = ws + 212992;
  const unsigned short* W4T = ws + 245760;

  float* zsL  = (float*)(smem + OFF_ZS);
  float* b4L  = (float*)(smem + OFF_B4);
  float* redL = (float*)(smem + OFF_RED);

  // per-row scalars straight to registers (each lane owns row lm)
  const int rr = row0 + lm;
  const float rw = rewards[rr];
  const float bt = bootstrap[rr];
  const float dc = discount[rr];

  // stage q_support / b4 (padded to 256, avoids OOB vector loads)
  zsL[tid] = (tid < 251) ? q_support[tid] : 0.f;
  b4L[tid] = (tid < 251) ? b4[tid] : 0.f;

  // stage X = concat(obs, actions) bf16 [16][160], swizzled (640 uint2)
  {
    unsigned char* Xb = smem + OFF_R;
    for (int qq = tid; qq < 640; qq += THREADS) {
      const int r  = qq / 40;
      const int c4 = (qq - r * 40) * 4;
      float4 v;
      if (c4 < 128) v = *(const float4*)(obs + (size_t)(row0 + r) * 128 + c4);
      else          v = *(const float4*)(actions + (size_t)(row0 + r) * 32 + (c4 - 128));
      uint2 w; w.x = pack2bf(v.x, v.y); w.y = pack2bf(v.z, v.w);
      int byte = r * 320 + c4 * 2;
      byte ^= ((r & 7) << 4);
      *(uint2*)(Xb + byte) = w;
    }
  }
  __syncthreads();

  // ---- layer 1: 512 feats, K=160; 128 feats/wave ----
  f32x4 acc1[8];
#pragma unroll
  for (int i = 0; i < 8; ++i) acc1[i] = f32x4{0.f, 0.f, 0.f, 0.f};
  gemm_w<160, 8>(W1T, smem + OFF_R, fq * 128, acc1);
  ln_silu_store<512, 8>(acc1, b1, g1, be1, smem + OFF_R, redL, fq * 128, fq);
  __syncthreads();

  // ---- layer 2: 256 feats, K=512; 64 feats/wave ----
  f32x4 acc2[4];
#pragma unroll
  for (int i = 0; i < 4; ++i) acc2[i] = f32x4{0.f, 0.f, 0.f, 0.f};
  gemm_w<512, 4>(W2T, smem + OFF_R, fq * 64, acc2);
  ln_silu_store<256, 4>(acc2, b2, g2, be2, smem + OFF_R, redL, fq * 64, fq);
  __syncthreads();

  // ---- layer 3: 128 feats, K=256; 32 feats/wave ----
  f32x4 acc3[2];
  acc3[0] = f32x4{0.f, 0.f, 0.f, 0.f};
  acc3[1] = f32x4{0.f, 0.f, 0.f, 0.f};
  gemm_w<256, 2>(W3T, smem + OFF_R, fq * 32, acc3);
  ln_silu_store<128, 2>(acc3, b3, g3, be3, smem + OFF_R, redL, fq * 32, fq);
  __syncthreads();

  // ---- layer 4: logits, 256pad feats, K=128; 64 feats/wave ----
  f32x4 acc4[4];
#pragma unroll
  for (int i = 0; i < 4; ++i) acc4[i] = f32x4{0.f, 0.f, 0.f, 0.f};
  gemm_w<128, 4>(W4T, smem + OFF_R, fq * 64, acc4);

  float lv[4][4];
#pragma unroll
  for (int ft = 0; ft < 4; ++ft) {
    const int f0 = fq * 64 + ft * 16 + kg * 4;
    const f32x4 bb = *(const f32x4*)(b4L + f0);
#pragma unroll
    for (int rg = 0; rg < 4; ++rg) {
      const int f = f0 + rg;
      lv[ft][rg] = (f < 251) ? (acc4[ft][rg] + bb[rg]) : -1e30f;
    }
  }

  // ---- softmax over 251 features per row (stride-5 padded reduction) ----
  {
    float m = lv[0][0];
#pragma unroll
    for (int ft = 0; ft < 4; ++ft)
#pragma unroll
      for (int rg = 0; rg < 4; ++rg) m = fmaxf(m, lv[ft][rg]);
    m = fmaxf(m, __shfl_xor(m, 16));
    m = fmaxf(m, __shfl_xor(m, 32));
    if (lane < 16) redL[lm * 5 + fq] = m;
  }
  __syncthreads();   // all waves past GEMM4's H3 reads; redL max visible

  // zero proj buffer (region R; overwrites H3 — dead now)
  float* projL = (float*)(smem + OFF_R);
  for (int i = tid; i < 16 * 251; i += THREADS) projL[i] = 0.f;

  float gm;
  {
    float m = redL[lm * 5];
#pragma unroll
    for (int w = 1; w < 4; ++w) m = fmaxf(m, redL[lm * 5 + w]);
    gm = m;
  }
  __syncthreads();   // redL reuse + proj zeros visible
  {
    float E = 0.f;
#pragma unroll
    for (int ft = 0; ft < 4; ++ft)
#pragma unroll
      for (int rg = 0; rg < 4; ++rg) {
        float e = __expf(lv[ft][rg] - gm);
        lv[ft][rg] = e;
        E += e;
      }
    E += __shfl_xor(E, 16); E += __shfl_xor(E, 32);
    if (lane < 16) redL[lm * 5 + fq] = E;
  }
  __syncthreads();
  float inv;
  {
    float E = 0.f;
#pragma unroll
    for (int w = 0; w < 4; ++w) E += redL[lm * 5 + w];
    inv = 1.0f / E;
  }

  // ---- C51 projection scatter (bit-exact bin math vs numpy) ----
  constexpr float DZF = 20.0f / 250.0f;
  const int base = lm * 251;
  const float bd = __fmul_rn(bt, dc);
#pragma unroll
  for (int ft = 0; ft < 4; ++ft) {
    const int f0 = fq * 64 + ft * 16 + kg * 4;
    const f32x4 z4 = *(const f32x4*)(zsL + f0);
#pragma unroll
    for (int rg = 0; rg < 4; ++rg) {
      const int f = f0 + rg;
      if (f < 251) {
        const float p = lv[ft][rg] * inv;
        float t = __fadd_rn(rw, __fmul_rn(bd, z4[rg]));
        t = fminf(fmaxf(t, -10.0f), 10.0f);
        const float bfr = __fdiv_rn(__fsub_rn(t, -10.0f), DZF);
        const float fl = floorf(bfr), fu = ceilf(bfr);
        int l = (int)fl, u = (int)fu;
        if (fl == fu) { if (l > 0) --l; else ++u; }
        atomicAdd(projL + base + l, p * ((float)u - bfr));
        atomicAdd(projL + base + u, p * (bfr - (float)l));
      }
    }
  }
  __syncthreads();

  // ---- write out: block slice contiguous (16*251 floats = 1004 float4) ----
  const float4* ps = (const float4*)projL;
  float4* po = (float4*)(out + (size_t)row0 * 251);
  for (int i = tid; i < 1004; i += THREADS) po[i] = ps[i];
}

extern "C" void kernel_launch(void* const* d_in, const int* in_sizes, int n_in,
                              void* d_out, int out_size, void* d_ws, size_t ws_size,
                              hipStream_t stream) {
  const float* obs  = (const float*)d_in[0];
  const float* act  = (const float*)d_in[1];
  const float* rew  = (const float*)d_in[2];
  const float* boot = (const float*)d_in[3];
  const float* disc = (const float*)d_in[4];
  const float* zs   = (const float*)d_in[5];
  const float* W1   = (const float*)d_in[6];
  const float* b1   = (const float*)d_in[7];
  const float* g1   = (const float*)d_in[8];
  const float* be1  = (const float*)d_in[9];
  const float* W2   = (const float*)d_in[10];
  const float* b2   = (const float*)d_in[11];
  const float* g2   = (const float*)d_in[12];
  const float* be2  = (const float*)d_in[13];
  const float* W3   = (const float*)d_in[14];
  const float* b3   = (const float*)d_in[15];
  const float* g3   = (const float*)d_in[16];
  const float* be3  = (const float*)d_in[17];
  const float* W4   = (const float*)d_in[18];
  const float* b4   = (const float*)d_in[19];
  unsigned short* wsp = (unsigned short*)d_ws;

  const int Bn = in_sizes[2];          // batch = 131072
  prep_kernel<<<(278528 + PREP_THREADS - 1) / PREP_THREADS, PREP_THREADS, 0, stream>>>(
      W1, W2, W3, W4, wsp);
  fused_kernel<<<Bn / 16, THREADS, 0, stream>>>(obs, act, rew, boot, disc, zs,
      b1, g1, be1, b2, g2, be2, b3, g3, be3, b4, wsp, (float*)d_out);
}

// Round 7
// 489.590 us; speedup vs baseline: 1.1321x; 1.1321x over previous
//
#include <hip/hip_runtime.h>

// C51 distributional Q target: operand-swapped MFMA (D = W * X^T), each lane
// owns 4 consecutive FEATURES of one batch ROW; LN/SiLU/softmax in registers.
// R7 = R5 base (32 rows/block, 4 waves, rt=2, 36KB LDS, 4 blocks/CU) +
// explicit DEPTH-3 ring-buffer pipeline in gemm_w (a-frags from L2 prefetched
// 2 items ahead, b-frags from LDS prefetched 2 ks ahead), FPG=2, and
// mul-by-reciprocal in the projection (placement is continuous in b).

#define THREADS 256
#define PREP_THREADS 256

typedef __attribute__((ext_vector_type(8))) short short8v;
typedef __attribute__((ext_vector_type(4))) float f32x4;

__device__ __forceinline__ unsigned short f2bf(float f) {
  union { float f; unsigned u; } v; v.f = f;
  unsigned u = v.u;
  u += 0x7fffu + ((u >> 16) & 1u);   // RNE
  return (unsigned short)(u >> 16);
}
// HW packed fp32->bf16 (RNE), 1 VALU inst for 2 values
__device__ __forceinline__ unsigned pack2bf(float a, float b) {
  unsigned r;
  asm("v_cvt_pk_bf16_f32 %0, %1, %2" : "=v"(r) : "v"(a), "v"(b));
  return r;
}

// ---------------- prep: weights fp32 [K][N] -> bf16 [N][K] in ws -------------
// W1T @0 (512x160), W2T @81920 (256x512), W3T @212992 (128x256),
// W4T @245760 (256x128, rows n>=251 zero-padded)
__global__ void prep_kernel(const float* __restrict__ W1, const float* __restrict__ W2,
                            const float* __restrict__ W3, const float* __restrict__ W4,
                            unsigned short* __restrict__ ws) {
  int i = blockIdx.x * PREP_THREADS + threadIdx.x;
  if (i < 81920) {
    int n = i / 160, k = i - n * 160;
    ws[i] = f2bf(W1[k * 512 + n]);
  } else if (i < 212992) {
    int j = i - 81920; int n = j >> 9, k = j & 511;
    ws[i] = f2bf(W2[k * 256 + n]);
  } else if (i < 245760) {
    int j = i - 212992; int n = j >> 8, k = j & 255;
    ws[i] = f2bf(W3[k * 128 + n]);
  } else if (i < 278528) {
    int j = i - 245760; int n = j >> 7, k = j & 127;
    ws[i] = (n < 251) ? f2bf(W4[k * 251 + n]) : (unsigned short)0;
  }
}

// LDS layout (bytes). ONE time-multiplexed 32KB region R @0:
//   X bf16 [32][160] swz -> H1 [32][512] swz -> H2 [32][256] swz ->
//   H3 [32][128] swz -> proj f32 [32][251]
// Every overwrite is fenced by the LN reduction's internal __syncthreads.
#define OFF_R   0
#define OFF_ZS  32768
#define OFF_B4  33792
#define OFF_RED 34816
#define LDS_TOTAL 36096

// GEMM: acc[ft][rt] += WT[fbase+ft*16+..][k] * H[rt*16+..][k]
// MFMA 16x16x32 bf16, A = weight rows (m=feature), B = act rows (n=batch row).
// D: lane&15 = batch row in tile, (lane>>4)*4+reg = feature in tile.
// Ring-buffer pipeline: a-frags prefetched PF=DEPTH-1 items ahead (L2 ~250cy),
// b-frags prefetched PB=DEPTH-1 ks ahead (LDS ~120cy). All ring indices are
// compile-time constants after full unroll (no scratch).
template<int KD, int NFT, int FPG, int DEPTH>
__device__ __forceinline__ void gemm_w(const unsigned short* __restrict__ WT,
                                       const unsigned char* __restrict__ Hb,
                                       int fbase, f32x4 (&acc)[NFT][2]) {
  const int lane = threadIdx.x & 63;
  const int lm = lane & 15, kg = lane >> 4;
  constexpr int KS  = KD / 32;
  constexpr int G   = NFT / FPG;
  constexpr int NIT = KS * G;
  constexpr int PF  = DEPTH - 1;   // a-frag item prefetch distance
  constexpr int PB  = DEPTH - 1;   // b-frag ks prefetch distance

  const int woff0 = (fbase + lm) * KD + kg * 8;
  // b-frag LDS byte offsets: per-rt, per-ks-parity (swizzle XOR covers bits
  // 4..6; bit6 of ks*64 folds into parity, higher bits advance by 128B/pair).
  int boff[2][2];
#pragma unroll
  for (int rt = 0; rt < 2; ++rt) {
    const int r = rt * 16 + lm;
    const int swz = (r & 7) << 4;
    const int base = r * (KD * 2) + kg * 16;
    boff[rt][0] = base ^ swz;
    boff[rt][1] = (base + 64) ^ swz;
  }

  short8v abuf[DEPTH][FPG];
  short8v bbuf[DEPTH][2];

  // prologue: b for ks = 0..PB-1, a for items 0..PF-1
#pragma unroll
  for (int ks = 0; ks < PB && ks < KS; ++ks) {
    const int koff = (ks >> 1) * 128;
#pragma unroll
    for (int rt = 0; rt < 2; ++rt)
      bbuf[ks % DEPTH][rt] = *(const short8v*)(Hb + boff[rt][ks & 1] + koff);
  }
#pragma unroll
  for (int p = 0; p < PF && p < NIT; ++p) {
    const int g = p % G, ks = p / G;
#pragma unroll
    for (int f = 0; f < FPG; ++f)
      abuf[p % DEPTH][f] =
          *(const short8v*)(WT + woff0 + (g * FPG + f) * (16 * KD) + ks * 32);
  }

#pragma unroll
  for (int it = 0; it < NIT; ++it) {
    const int ks = it / G, g = it % G;
    // b prefetch: at first item of each ks, fetch ks+PB
    if (g == 0 && ks + PB < KS) {
      const int nks = ks + PB;
      const int koff = (nks >> 1) * 128;
#pragma unroll
      for (int rt = 0; rt < 2; ++rt)
        bbuf[nks % DEPTH][rt] = *(const short8v*)(Hb + boff[rt][nks & 1] + koff);
    }
    // a prefetch: item it+PF
    if (it + PF < NIT) {
      const int nit = it + PF;
      const int ng = nit % G, nks = nit / G;
#pragma unroll
      for (int f = 0; f < FPG; ++f)
        abuf[nit % DEPTH][f] =
            *(const short8v*)(WT + woff0 + (ng * FPG + f) * (16 * KD) + nks * 32);
    }
    // compute item it
#pragma unroll
    for (int f = 0; f < FPG; ++f) {
      const int ft = g * FPG + f;
      acc[ft][0] = __builtin_amdgcn_mfma_f32_16x16x32_bf16(
          abuf[it % DEPTH][f], bbuf[ks % DEPTH][0], acc[ft][0], 0, 0, 0);
      acc[ft][1] = __builtin_amdgcn_mfma_f32_16x16x32_bf16(
          abuf[it % DEPTH][f], bbuf[ks % DEPTH][1], acc[ft][1], 0, 0, 0);
    }
  }
}

// bias + LayerNorm + SiLU entirely in registers, then one packed b64 store
// per (ft, rt) into swizzled LDS [32][ND] bf16. 4 waves reduce via redL
// (stride 9). Internal barrier doubles as the region-reuse fence.
template<int ND, int NFT>
__device__ __forceinline__ void ln_silu_store(
    f32x4 (&acc)[NFT][2],
    const float* __restrict__ bias, const float* __restrict__ g,
    const float* __restrict__ be, unsigned char* __restrict__ Hb,
    float* __restrict__ redL, int fbase, int fq)
{
  const int lane = threadIdx.x & 63;
  const int lm = lane & 15, kg = lane >> 4;
  float s[2] = {0.f, 0.f}, q[2] = {0.f, 0.f};
#pragma unroll
  for (int ft = 0; ft < NFT; ++ft) {
    const int f0 = fbase + ft * 16 + kg * 4;
    const f32x4 bb = *(const f32x4*)(bias + f0);
#pragma unroll
    for (int rt = 0; rt < 2; ++rt)
#pragma unroll
      for (int rg = 0; rg < 4; ++rg) {
        float x = acc[ft][rt][rg] + bb[rg];
        acc[ft][rt][rg] = x;
        s[rt] += x; q[rt] += x * x;
      }
  }
#pragma unroll
  for (int rt = 0; rt < 2; ++rt) {
    s[rt] += __shfl_xor(s[rt], 16); s[rt] += __shfl_xor(s[rt], 32);
    q[rt] += __shfl_xor(q[rt], 16); q[rt] += __shfl_xor(q[rt], 32);
  }
  if (lane < 16) {
#pragma unroll
    for (int rt = 0; rt < 2; ++rt) {
      redL[(rt * 16 + lm) * 9 + fq * 2    ] = s[rt];
      redL[(rt * 16 + lm) * 9 + fq * 2 + 1] = q[rt];
    }
  }
  __syncthreads();
  float mean[2], rstd[2];
#pragma unroll
  for (int rt = 0; rt < 2; ++rt) {
    const int row = rt * 16 + lm;
    float S = 0.f, Q = 0.f;
#pragma unroll
    for (int w = 0; w < 4; ++w) {
      S += redL[row * 9 + w * 2];
      Q += redL[row * 9 + w * 2 + 1];
    }
    float m = S * (1.0f / ND);
    float v = Q * (1.0f / ND) - m * m;
    mean[rt] = m; rstd[rt] = rsqrtf(v + 1e-5f);
  }
#pragma unroll
  for (int ft = 0; ft < NFT; ++ft) {
    const int f0 = fbase + ft * 16 + kg * 4;
    const f32x4 g4 = *(const f32x4*)(g + f0);
    const f32x4 e4 = *(const f32x4*)(be + f0);
#pragma unroll
    for (int rt = 0; rt < 2; ++rt) {
      const int row = rt * 16 + lm;
      float h[4];
#pragma unroll
      for (int rg = 0; rg < 4; ++rg) {
        float y = (acc[ft][rt][rg] - mean[rt]) * rstd[rt] * g4[rg] + e4[rg];
        h[rg] = y * (1.0f / (1.0f + __expf(-y)));
      }
      uint2 w; w.x = pack2bf(h[0], h[1]); w.y = pack2bf(h[2], h[3]);
      int byte = row * (ND * 2) + f0 * 2;
      byte ^= ((row & 7) << 4);
      *(uint2*)(Hb + byte) = w;
    }
  }
}

__global__ __launch_bounds__(THREADS, 4) void fused_kernel(
    const float* __restrict__ obs, const float* __restrict__ actions,
    const float* __restrict__ rewards, const float* __restrict__ bootstrap,
    const float* __restrict__ discount, const float* __restrict__ q_support,
    const float* __restrict__ b1, const float* __restrict__ g1, const float* __restrict__ be1,
    const float* __restrict__ b2, const float* __restrict__ g2, const float* __restrict__ be2,
    const float* __restrict__ b3, const float* __restrict__ g3, const float* __restrict__ be3,
    const float* __restrict__ b4,
    const unsigned short* __restrict__ ws,
    float* __restrict__ out)
{
  __shared__ __align__(16) unsigned char smem[LDS_TOTAL];
  const int tid  = threadIdx.x;
  const int fq   = tid >> 6;          // wave = feature-quarter, 0..3
  const int lane = tid & 63;
  const int lm   = lane & 15;
  const int kg   = lane >> 4;
  const int row0 = blockIdx.x * 32;

  const unsigned short* W1T = ws;
  const unsigned short* W2T = ws + 81920;
  const unsigned short* W3T = ws + 212992;
  const unsigned short* W4T = ws + 245760;

  float* zsL  = (float*)(smem + OFF_ZS);
  float* b4L  = (float*)(smem + OFF_B4);
  float* redL = (float*)(smem + OFF_RED);

  // per-row scalars straight to registers (each lane owns rows rt*16+lm)
  float rw[2], bt[2], dc[2];
#pragma unroll
  for (int rt = 0; rt < 2; ++rt) {
    const int r = row0 + rt * 16 + lm;
    rw[rt] = rewards[r]; bt[rt] = bootstrap[r]; dc[rt] = discount[r];
  }

  // stage q_support / b4 (padded to 256, avoids OOB vector loads)
  zsL[tid] = (tid < 251) ? q_support[tid] : 0.f;
  b4L[tid] = (tid < 251) ? b4[tid] : 0.f;

  // stage X = concat(obs, actions) bf16 [32][160], swizzled (1280 uint2)
  {
    unsigned char* Xb = smem + OFF_R;
#pragma unroll
    for (int it = 0; it < 5; ++it) {
      const int qq = it * THREADS + tid;     // 0..1279, 40 float4 per row
      const int r  = qq / 40;
      const int c4 = (qq - r * 40) * 4;
      float4 v;
      if (c4 < 128) v = *(const float4*)(obs + (size_t)(row0 + r) * 128 + c4);
      else          v = *(const float4*)(actions + (size_t)(row0 + r) * 32 + (c4 - 128));
      uint2 w; w.x = pack2bf(v.x, v.y); w.y = pack2bf(v.z, v.w);
      int byte = r * 320 + c4 * 2;
      byte ^= ((r & 7) << 4);
      *(uint2*)(Xb + byte) = w;
    }
  }
  __syncthreads();

  // ---- layer 1: 512 feats, K=160; 128 feats/wave (depth-2: acc is 64 VGPR)
  f32x4 acc1[8][2];
#pragma unroll
  for (int i = 0; i < 8; ++i) { acc1[i][0] = f32x4{0,0,0,0}; acc1[i][1] = f32x4{0,0,0,0}; }
  gemm_w<160, 8, 2, 2>(W1T, smem + OFF_R, fq * 128, acc1);
  ln_silu_store<512, 8>(acc1, b1, g1, be1, smem + OFF_R, redL, fq * 128, fq);
  __syncthreads();

  // ---- layer 2: 256 feats, K=512; 64 feats/wave (depth-3) ----
  f32x4 acc2[4][2];
#pragma unroll
  for (int i = 0; i < 4; ++i) { acc2[i][0] = f32x4{0,0,0,0}; acc2[i][1] = f32x4{0,0,0,0}; }
  gemm_w<512, 4, 2, 3>(W2T, smem + OFF_R, fq * 64, acc2);
  ln_silu_store<256, 4>(acc2, b2, g2, be2, smem + OFF_R, redL, fq * 64, fq);
  __syncthreads();

  // ---- layer 3: 128 feats, K=256; 32 feats/wave (depth-3) ----
  f32x4 acc3[2][2];
#pragma unroll
  for (int i = 0; i < 2; ++i) { acc3[i][0] = f32x4{0,0,0,0}; acc3[i][1] = f32x4{0,0,0,0}; }
  gemm_w<256, 2, 2, 3>(W3T, smem + OFF_R, fq * 32, acc3);
  ln_silu_store<128, 2>(acc3, b3, g3, be3, smem + OFF_R, redL, fq * 32, fq);
  __syncthreads();

  // ---- layer 4: logits, 256pad feats, K=128; 64 feats/wave (depth-3) ----
  f32x4 acc4[4][2];
#pragma unroll
  for (int i = 0; i < 4; ++i) { acc4[i][0] = f32x4{0,0,0,0}; acc4[i][1] = f32x4{0,0,0,0}; }
  gemm_w<128, 4, 2, 3>(W4T, smem + OFF_R, fq * 64, acc4);

  float lv[4][2][4];
#pragma unroll
  for (int ft = 0; ft < 4; ++ft) {
    const int f0 = fq * 64 + ft * 16 + kg * 4;
    const f32x4 bb = *(const f32x4*)(b4L + f0);
#pragma unroll
    for (int rt = 0; rt < 2; ++rt)
#pragma unroll
      for (int rg = 0; rg < 4; ++rg) {
        const int f = f0 + rg;
        lv[ft][rt][rg] = (f < 251) ? (acc4[ft][rt][rg] + bb[rg]) : -1e30f;
      }
  }

  // ---- softmax over 251 features per row (stride-5 padded reduction) ----
#pragma unroll
  for (int rt = 0; rt < 2; ++rt) {
    float m = lv[0][rt][0];
#pragma unroll
    for (int ft = 0; ft < 4; ++ft)
#pragma unroll
      for (int rg = 0; rg < 4; ++rg) m = fmaxf(m, lv[ft][rt][rg]);
    m = fmaxf(m, __shfl_xor(m, 16));
    m = fmaxf(m, __shfl_xor(m, 32));
    if (lane < 16) redL[(rt * 16 + lm) * 5 + fq] = m;
  }
  __syncthreads();   // all waves past GEMM4's H3 reads; redL max visible

  // zero proj buffer (region R; overwrites H3 — dead now)
  float* projL = (float*)(smem + OFF_R);
  for (int i = tid; i < 32 * 251; i += THREADS) projL[i] = 0.f;

  float gm[2];
#pragma unroll
  for (int rt = 0; rt < 2; ++rt) {
    const int row = rt * 16 + lm;
    float m = redL[row * 5];
#pragma unroll
    for (int w = 1; w < 4; ++w) m = fmaxf(m, redL[row * 5 + w]);
    gm[rt] = m;
  }
  __syncthreads();   // redL reuse + proj zeros visible
#pragma unroll
  for (int rt = 0; rt < 2; ++rt) {
    float E = 0.f;
#pragma unroll
    for (int ft = 0; ft < 4; ++ft)
#pragma unroll
      for (int rg = 0; rg < 4; ++rg) {
        float e = __expf(lv[ft][rt][rg] - gm[rt]);
        lv[ft][rt][rg] = e;
        E += e;
      }
    E += __shfl_xor(E, 16); E += __shfl_xor(E, 32);
    if (lane < 16) redL[(rt * 16 + lm) * 5 + fq] = E;
  }
  __syncthreads();
  float inv[2];
#pragma unroll
  for (int rt = 0; rt < 2; ++rt) {
    const int row = rt * 16 + lm;
    float E = 0.f;
#pragma unroll
    for (int w = 0; w < 4; ++w) E += redL[row * 5 + w];
    inv[rt] = 1.0f / E;
  }

  // ---- C51 projection scatter ----
  // b = (t+10) * (1/DZ): <=1ulp off the reference's correctly-rounded divide;
  // the two-point interpolation is continuous in b (incl. integer crossings),
  // so the output perturbation is O(1e-7) -- far under threshold.
  constexpr float DZF = 20.0f / 250.0f;
  constexpr float INVDZ = 1.0f / DZF;
#pragma unroll
  for (int ft = 0; ft < 4; ++ft) {
    const int f0 = fq * 64 + ft * 16 + kg * 4;
    const f32x4 z4 = *(const f32x4*)(zsL + f0);
#pragma unroll
    for (int rt = 0; rt < 2; ++rt) {
      const int base = (rt * 16 + lm) * 251;
      const float bd = __fmul_rn(bt[rt], dc[rt]);
#pragma unroll
      for (int rg = 0; rg < 4; ++rg) {
        const int f = f0 + rg;
        if (f < 251) {
          const float p = lv[ft][rt][rg] * inv[rt];
          float t = __fadd_rn(rw[rt], __fmul_rn(bd, z4[rg]));
          t = fminf(fmaxf(t, -10.0f), 10.0f);
          const float bfr = __fmul_rn(__fsub_rn(t, -10.0f), INVDZ);
          const float fl = floorf(bfr), fu = ceilf(bfr);
          int l = (int)fl, u = (int)fu;
          if (fl == fu) { if (l > 0) --l; else ++u; }
          atomicAdd(projL + base + l, p * ((float)u - bfr));
          atomicAdd(projL + base + u, p * (bfr - (float)l));
        }
      }
    }
  }
  __syncthreads();

  // ---- write out: block slice contiguous (32*251 floats = 2008 float4) ----
  const float4* ps = (const float4*)projL;
  float4* po = (float4*)(out + (size_t)row0 * 251);
  for (int i = tid; i < 2008; i += THREADS) po[i] = ps[i];
}

extern "C" void kernel_launch(void* const* d_in, const int* in_sizes, int n_in,
                              void* d_out, int out_size, void* d_ws, size_t ws_size,
                              hipStream_t stream) {
  const float* obs  = (const float*)d_in[0];
  const float* act  = (const float*)d_in[1];
  const float* rew  = (const float*)d_in[2];
  const float* boot = (const float*)d_in[3];
  const float* disc = (const float*)d_in[4];
  const float* zs   = (const float*)d_in[5];
  const float* W1   = (const float*)d_in[6];
  const float* b1   = (const float*)d_in[7];
  const float* g1   = (const float*)d_in[8];
  const float* be1  = (const float*)d_in[9];
  const float* W2   = (const float*)d_in[10];
  const float* b2   = (const float*)d_in[11];
  const float* g2   = (const float*)d_in[12];
  const float* be2  = (const float*)d_in[13];
  const float* W3   = (const float*)d_in[14];
  const float* b3   = (const float*)d_in[15];
  const float* g3   = (const float*)d_in[16];
  const float* be3  = (const float*)d_in[17];
  const float* W4   = (const float*)d_in[18];
  const float* b4   = (const float*)d_in[19];
  unsigned short* wsp = (unsigned short*)d_ws;

  const int Bn = in_sizes[2];          // batch = 131072
  prep_kernel<<<(278528 + PREP_THREADS - 1) / PREP_THREADS, PREP_THREADS, 0, stream>>>(
      W1, W2, W3, W4, wsp);
  fused_kernel<<<Bn / 32, THREADS, 0, stream>>>(obs, act, rew, boot, disc, zs,
      b1, g1, be1, b2, g2, be2, b3, g3, be3, b4, wsp, (float*)d_out);
}